// Round 5
// baseline (927.478 us; speedup 1.0000x reference)
//
#include <hip/hip_runtime.h>
#include <hip/hip_bf16.h>
#include <math.h>

typedef short short8 __attribute__((ext_vector_type(8)));
typedef float floatx4 __attribute__((ext_vector_type(4)));
typedef unsigned int u32_g __attribute__((address_space(1)));
typedef unsigned int u32_l __attribute__((address_space(3)));

__device__ __forceinline__ void gl_lds16(const void* g, void* l) {
    __builtin_amdgcn_global_load_lds((const u32_g*)g, (u32_l*)l, 16, 0, 0);
}

#define NB 2
#define TSEQ 1024
#define DIM 1024
#define NHEAD 16
#define HS 64
#define NEXP 8
#define FF 4096
#define NTOK (NB*TSEQ)          // 2048
#define MAXSLOT 5120            // 4096 + 8*127 padded, rounded to 40*128

// ---------------- workspace offsets (bytes) ----------------
#define OFF_Q      ((size_t)0)           // 8MB; dead after scores -> reused as attnB (pv z=1 partial)
#define OFF_K      ((size_t)8388608)
#define OFF_V      ((size_t)16777216)
#define OFF_ATTN   ((size_t)25165824)
#define OFF_Y      ((size_t)33554432)
#define OFF_YBF    ((size_t)41943040)
#define OFF_W1T    ((size_t)46137344)    // 64MB bf16 [E][FF][D]; dead after gemm1 -> eoA/eoB
#define OFF_MOE    ((size_t)113246208)   // now only slot_of (16KB)
#define OFF_TOPKE  ((size_t)121634816)
#define OFF_TOPKW  ((size_t)121651200)
#define OFF_CNT    ((size_t)121667584)
#define OFF_PO     ((size_t)121667648)
#define OFF_CUR    ((size_t)121667712)
#define OFF_SLOTT  ((size_t)121667776)
#define OFF_SLOTW  ((size_t)121688256)
#define OFF_S      ((size_t)121708800)   // 128MB fp32 scores/probs
// Dead-time reuse of the S region:
#define OFF_XHI    (OFF_S)
#define OFF_XLO    (OFF_S + 4194304)
#define OFF_WTHI   (OFF_S + 8388608)     // 6MB bf16 [3][1024][1024]
#define OFF_WTLO   (OFF_S + 14680064)
#define OFF_W2T    (OFF_S)               // 64MB bf16 [E][D][FF]
#define OFF_H      (OFF_S + 67108864)    // 40MB bf16 [MAXSLOT][FF]

#define OFF_ATTNB  (OFF_Q)               // pv z=1 partial output
#define OFF_SLOTOF (OFF_MOE)             // [4096] int: slot index per (token,k)
#define OFF_EOA    (OFF_W1T)             // 21MB fp32 [MAXSLOT][D] (split-K kz=0, includes b2)
#define OFF_EOB    (OFF_W1T + 20971520)  // 21MB fp32 (kz=1)

// ================= split x into bf16 hi/lo =================
__global__ __launch_bounds__(256) void xsplit_kernel(
    const float* __restrict__ x, __hip_bfloat16* __restrict__ xhi, __hip_bfloat16* __restrict__ xlo)
{
    int idx = (blockIdx.x * 256 + threadIdx.x) * 4;
    float4 v = *(const float4*)(x + idx);
    float vv[4] = {v.x, v.y, v.z, v.w};
    union { ushort u[4]; ushort4 q; } hi, lo;
    #pragma unroll
    for (int l = 0; l < 4; ++l) {
        __hip_bfloat16 hb = __float2bfloat16(vv[l]);
        hi.u[l] = *(const ushort*)&hb;
        float r = vv[l] - __bfloat162float(hb);
        __hip_bfloat16 lb = __float2bfloat16(r);
        lo.u[l] = *(const ushort*)&lb;
    }
    *(ushort4*)((ushort*)xhi + idx) = hi.q;
    *(ushort4*)((ushort*)xlo + idx) = lo.q;
}

// ====== transpose Wq/Wk/Wv [16][1024][64] -> Wt[mat][(h*64+f)][d] bf16 hi/lo ======
__global__ __launch_bounds__(256) void wsplit_kernel(
    const float* __restrict__ Wq, const float* __restrict__ Wk, const float* __restrict__ Wv,
    __hip_bfloat16* __restrict__ Wthi, __hip_bfloat16* __restrict__ Wtlo)
{
    int z = blockIdx.z, mat = z >> 4, hh = z & 15;
    const float* W = (mat == 0) ? Wq : ((mat == 1) ? Wk : Wv);
    const float* slab = W + (size_t)hh * DIM * HS;              // [1024][64]
    ushort* ohi = (ushort*)Wthi + (size_t)mat * (DIM * DIM) + (size_t)hh * HS * DIM;
    ushort* olo = (ushort*)Wtlo + (size_t)mat * (DIM * DIM) + (size_t)hh * HS * DIM;
    int c0 = blockIdx.x * 32, r0 = blockIdx.y * 32;
    __shared__ float tile[32][33];
    int t = threadIdx.x, i = t >> 3, j4 = (t & 7) * 4;
    float4 v4 = *(const float4*)(slab + (size_t)(r0 + i) * HS + c0 + j4);
    tile[i][j4] = v4.x; tile[i][j4+1] = v4.y; tile[i][j4+2] = v4.z; tile[i][j4+3] = v4.w;
    __syncthreads();
    union { ushort u[4]; ushort4 q; } hi, lo;
    #pragma unroll
    for (int l = 0; l < 4; ++l) {
        float xv = tile[j4 + l][i];
        __hip_bfloat16 hb = __float2bfloat16(xv);
        hi.u[l] = *(const ushort*)&hb;
        float r = xv - __bfloat162float(hb);
        __hip_bfloat16 lb = __float2bfloat16(r);
        lo.u[l] = *(const ushort*)&lb;
    }
    *(ushort4*)(ohi + (size_t)(c0 + i) * DIM + r0 + j4) = hi.q;
    *(ushort4*)(olo + (size_t)(c0 + i) * DIM + r0 + j4) = lo.q;
}

// ================= QKV via bf16x2-split MFMA =================
__global__ __launch_bounds__(256) void qkv_mfma(
    const __hip_bfloat16* __restrict__ xhi, const __hip_bfloat16* __restrict__ xlo,
    const __hip_bfloat16* __restrict__ Wthi, const __hip_bfloat16* __restrict__ Wtlo,
    float* __restrict__ Q, float* __restrict__ Kb, float* __restrict__ V)
{
    int mat = blockIdx.z;
    const __hip_bfloat16* Bhg = Wthi + (size_t)mat * (DIM * DIM);
    const __hip_bfloat16* Blg = Wtlo + (size_t)mat * (DIM * DIM);
    float* O = (mat == 0) ? Q : ((mat == 1) ? Kb : V);
    int n0 = blockIdx.x * 64, m0 = blockIdx.y * 128;
    int t = threadIdx.x, wave = t >> 6, lane = t & 63;
    __shared__ __hip_bfloat16 Ah[128][32];
    __shared__ __hip_bfloat16 Al[128][32];
    __shared__ __hip_bfloat16 Bh[64][32];
    __shared__ __hip_bfloat16 Bl[64][32];
    const __hip_bfloat16 *gAh[2], *gAl[2];
    __hip_bfloat16 *lAh[2], *lAl[2];
    #pragma unroll
    for (int p = 0; p < 2; ++p) {
        int lin = p * 256 + t, row = lin >> 2, seg = lin & 3;
        gAh[p] = xhi + (size_t)(m0 + row) * DIM + seg * 8;
        gAl[p] = xlo + (size_t)(m0 + row) * DIM + seg * 8;
        int cb = p * 256 + wave * 64;
        lAh[p] = &Ah[0][0] + (size_t)cb * 8;
        lAl[p] = &Al[0][0] + (size_t)cb * 8;
    }
    const __hip_bfloat16* gBh = Bhg + (size_t)(n0 + (t >> 2)) * DIM + (t & 3) * 8;
    const __hip_bfloat16* gBl = Blg + (size_t)(n0 + (t >> 2)) * DIM + (t & 3) * 8;
    __hip_bfloat16* lBh = &Bh[0][0] + (size_t)(wave * 64) * 8;
    __hip_bfloat16* lBl = &Bl[0][0] + (size_t)(wave * 64) * 8;

    int wr = (wave >> 1) * 64, wcl = (wave & 1) * 32;
    int lrow = lane & 15, quad = lane >> 4;
    floatx4 acc[4][2];
    #pragma unroll
    for (int i = 0; i < 4; ++i)
        #pragma unroll
        for (int j = 0; j < 2; ++j) acc[i][j] = (floatx4){0.f, 0.f, 0.f, 0.f};

    for (int k0 = 0; k0 < DIM; k0 += 32) {
        __syncthreads();
        gl_lds16(gAh[0] + k0, lAh[0]); gl_lds16(gAh[1] + k0, lAh[1]);
        gl_lds16(gAl[0] + k0, lAl[0]); gl_lds16(gAl[1] + k0, lAl[1]);
        gl_lds16(gBh + k0, lBh);       gl_lds16(gBl + k0, lBl);
        __syncthreads();
        short8 ah[4], al[4], bh[2], bl[2];
        #pragma unroll
        for (int i = 0; i < 4; ++i) {
            ah[i] = *(const short8*)(&Ah[wr + i * 16 + lrow][quad * 8]);
            al[i] = *(const short8*)(&Al[wr + i * 16 + lrow][quad * 8]);
        }
        #pragma unroll
        for (int j = 0; j < 2; ++j) {
            bh[j] = *(const short8*)(&Bh[wcl + j * 16 + lrow][quad * 8]);
            bl[j] = *(const short8*)(&Bl[wcl + j * 16 + lrow][quad * 8]);
        }
        #pragma unroll
        for (int i = 0; i < 4; ++i)
            #pragma unroll
            for (int j = 0; j < 2; ++j) {
                acc[i][j] = __builtin_amdgcn_mfma_f32_16x16x32_bf16(ah[i], bh[j], acc[i][j], 0, 0, 0);
                acc[i][j] = __builtin_amdgcn_mfma_f32_16x16x32_bf16(ah[i], bl[j], acc[i][j], 0, 0, 0);
                acc[i][j] = __builtin_amdgcn_mfma_f32_16x16x32_bf16(al[i], bh[j], acc[i][j], 0, 0, 0);
            }
    }
    #pragma unroll
    for (int i = 0; i < 4; ++i)
        #pragma unroll
        for (int j = 0; j < 2; ++j) {
            int ng = n0 + wcl + j * 16 + lrow;
            int hh = ng >> 6, f = ng & 63;
            #pragma unroll
            for (int r = 0; r < 4; ++r) {
                int mg = m0 + wr + i * 16 + quad * 4 + r;
                int bb = mg >> 10, tt = mg & 1023;
                O[(((size_t)bb * NHEAD + hh) * TSEQ + tt) * HS + f] = acc[i][j][r];
            }
        }
}

// ================= causal scores: S = Q K^T / 32 (lower tiles) =================
__global__ __launch_bounds__(256) void scores_kernel(
    const float* __restrict__ Q, const float* __restrict__ Kb, float* __restrict__ S)
{
    int tri = blockIdx.x, bh = blockIdx.y;
    int mt = 0; while (((mt + 1) * (mt + 2)) / 2 <= tri) ++mt;
    int nt = tri - (mt * (mt + 1)) / 2;
    int m0 = mt * 128, n0 = nt * 128;
    const float* Qb = Q + (size_t)bh * TSEQ * HS;
    const float* Kh = Kb + (size_t)bh * TSEQ * HS;
    float* Sb = S + (size_t)bh * TSEQ * TSEQ;
    __shared__ float As[16][132];
    __shared__ float Bs[16][132];
    int t = threadIdx.x, tx = t & 15, ty = t >> 4;
    float acc[8][8] = {{0.f}};
    for (int k0 = 0; k0 < HS; k0 += 16) {
        #pragma unroll
        for (int pss = 0; pss < 2; ++pss) {
            int lin = pss * 256 + t, m = lin >> 2, c = lin & 3;
            float4 v4 = *(const float4*)(Qb + (size_t)(m0 + m) * HS + k0 + c * 4);
            As[c*4+0][m] = v4.x; As[c*4+1][m] = v4.y; As[c*4+2][m] = v4.z; As[c*4+3][m] = v4.w;
        }
        #pragma unroll
        for (int pss = 0; pss < 2; ++pss) {
            int lin = pss * 256 + t, s = lin >> 2, c = lin & 3;
            float4 v4 = *(const float4*)(Kh + (size_t)(n0 + s) * HS + k0 + c * 4);
            Bs[c*4+0][s] = v4.x; Bs[c*4+1][s] = v4.y; Bs[c*4+2][s] = v4.z; Bs[c*4+3][s] = v4.w;
        }
        __syncthreads();
        #pragma unroll
        for (int kk = 0; kk < 16; ++kk) {
            float a[8], b[8];
            *(float4*)a       = *(const float4*)(&As[kk][ty * 4]);
            *(float4*)(a + 4) = *(const float4*)(&As[kk][64 + ty * 4]);
            *(float4*)b       = *(const float4*)(&Bs[kk][tx * 4]);
            *(float4*)(b + 4) = *(const float4*)(&Bs[kk][64 + tx * 4]);
            #pragma unroll
            for (int i = 0; i < 8; ++i)
                #pragma unroll
                for (int j = 0; j < 8; ++j) acc[i][j] += a[i] * b[j];
        }
        __syncthreads();
    }
    const float scale = 0.03125f;  // D^-0.5
    #pragma unroll
    for (int i = 0; i < 8; ++i) {
        int r = m0 + ((i < 4) ? ty * 4 + i : 64 + ty * 4 + (i - 4));
        #pragma unroll
        for (int jg = 0; jg < 2; ++jg) {
            int cb = n0 + ((jg == 0) ? tx * 4 : 64 + tx * 4);
            float4 v4 = make_float4(acc[i][jg*4+0]*scale, acc[i][jg*4+1]*scale,
                                    acc[i][jg*4+2]*scale, acc[i][jg*4+3]*scale);
            *(float4*)(Sb + (size_t)r * TSEQ + cb) = v4;
        }
    }
}

// ====== causal row softmax, in place; writes only up to the causal tile edge ======
__global__ __launch_bounds__(256) void softmax_kernel(float* __restrict__ S)
{
    int row = blockIdx.x, bh = row >> 10, r = row & 1023;
    float* p = S + ((size_t)bh * TSEQ + r) * TSEQ;
    int len = r + 1, t = threadIdx.x;
    int klim = (r & ~127) + 128;   // pv reads cols [0, klim) for this row
    float v[4]; float mx = -1e30f;
    #pragma unroll
    for (int i = 0; i < 4; ++i) { int c = t + i * 256; v[i] = (c < len) ? p[c] : -1e30f; mx = fmaxf(mx, v[i]); }
    __shared__ float redA[4];
    #pragma unroll
    for (int off = 32; off; off >>= 1) mx = fmaxf(mx, __shfl_down(mx, off));
    if ((t & 63) == 0) redA[t >> 6] = mx;
    __syncthreads();
    mx = fmaxf(fmaxf(redA[0], redA[1]), fmaxf(redA[2], redA[3]));
    float sum = 0.f;
    #pragma unroll
    for (int i = 0; i < 4; ++i) { int c = t + i * 256; float e = (c < len) ? expf(v[i] - mx) : 0.f; v[i] = e; sum += e; }
    __shared__ float redB[4];
    #pragma unroll
    for (int off = 32; off; off >>= 1) sum += __shfl_down(sum, off);
    if ((t & 63) == 0) redB[t >> 6] = sum;
    __syncthreads();
    float inv = 1.f / (redB[0] + redB[1] + redB[2] + redB[3]);
    #pragma unroll
    for (int i = 0; i < 4; ++i) { int c = t + i * 256; if (c < klim) p[c] = v[i] * inv; }
}

// ====== PV: attn = P V, split-K z=2 (z=0 -> attn, z=1 -> attnB; ln1 sums) ======
__global__ __launch_bounds__(256) void pv_kernel(
    const float* __restrict__ S, const float* __restrict__ V,
    float* __restrict__ attn, float* __restrict__ attnB)
{
    int mt = blockIdx.x, bh = blockIdx.y, z = blockIdx.z;
    int m0 = mt * 128;
    int half = (m0 >> 1) + 64;                 // multiple of 64
    int kbeg = z ? half : 0;
    int kend = z ? (m0 + 128) : half;
    float* O = z ? attnB : attn;
    const float* P = S + (size_t)bh * TSEQ * TSEQ;
    const float* Vb = V + (size_t)bh * TSEQ * HS;
    __shared__ float As[16][132];
    __shared__ float Bs[16][68];
    int t = threadIdx.x, tx = t & 15, ty = t >> 4;
    float acc[8][4] = {{0.f}};
    for (int k0 = kbeg; k0 < kend; k0 += 16) {
        #pragma unroll
        for (int pss = 0; pss < 2; ++pss) {
            int lin = pss * 256 + t, m = lin >> 2, c = lin & 3;
            float4 v4 = *(const float4*)(P + (size_t)(m0 + m) * TSEQ + k0 + c * 4);
            As[c*4+0][m] = v4.x; As[c*4+1][m] = v4.y; As[c*4+2][m] = v4.z; As[c*4+3][m] = v4.w;
        }
        { int kk = t >> 4, c = t & 15;
          float4 v4 = *(const float4*)(Vb + (size_t)(k0 + kk) * HS + c * 4);
          *(float4*)(&Bs[kk][c * 4]) = v4; }
        __syncthreads();
        #pragma unroll
        for (int kk = 0; kk < 16; ++kk) {
            float a[8], b[4];
            *(float4*)a       = *(const float4*)(&As[kk][ty * 4]);
            *(float4*)(a + 4) = *(const float4*)(&As[kk][64 + ty * 4]);
            *(float4*)b       = *(const float4*)(&Bs[kk][tx * 4]);
            #pragma unroll
            for (int i = 0; i < 8; ++i)
                #pragma unroll
                for (int j = 0; j < 4; ++j) acc[i][j] += a[i] * b[j];
        }
        __syncthreads();
    }
    int b = bh >> 4, hh = bh & 15;
    #pragma unroll
    for (int i = 0; i < 8; ++i) {
        int r = m0 + ((i < 4) ? ty * 4 + i : 64 + ty * 4 + (i - 4));
        float4 v4 = make_float4(acc[i][0], acc[i][1], acc[i][2], acc[i][3]);
        *(float4*)(O + ((size_t)b * TSEQ + r) * DIM + hh * HS + tx * 4) = v4;
    }
}

// ====== ln1: y = x + layernorm(attn+attnB)*g+b; also y_bf16 ======
__global__ __launch_bounds__(256) void ln1_kernel(
    const float* __restrict__ x, const float* __restrict__ attn, const float* __restrict__ attnB,
    const float* __restrict__ g, const float* __restrict__ bta,
    float* __restrict__ y, __hip_bfloat16* __restrict__ ybf)
{
    int n = blockIdx.x, t = threadIdx.x;
    const float* a = attn + (size_t)n * DIM;
    const float* aB = attnB + (size_t)n * DIM;
    float v[4]; float s = 0.f;
    #pragma unroll
    for (int i = 0; i < 4; ++i) { int c = t + i * 256; v[i] = a[c] + aB[c]; s += v[i]; }
    __shared__ float redA[4];
    #pragma unroll
    for (int off = 32; off; off >>= 1) s += __shfl_down(s, off);
    if ((t & 63) == 0) redA[t >> 6] = s;
    __syncthreads();
    float mean = (redA[0] + redA[1] + redA[2] + redA[3]) * (1.f / 1024.f);
    float s2 = 0.f;
    #pragma unroll
    for (int i = 0; i < 4; ++i) { float d = v[i] - mean; s2 += d * d; }
    __shared__ float redB[4];
    #pragma unroll
    for (int off = 32; off; off >>= 1) s2 += __shfl_down(s2, off);
    if ((t & 63) == 0) redB[t >> 6] = s2;
    __syncthreads();
    float rstd = rsqrtf((redB[0] + redB[1] + redB[2] + redB[3]) * (1.f / 1024.f) + 1e-5f);
    #pragma unroll
    for (int i = 0; i < 4; ++i) {
        int d = t + i * 256;
        float val = x[(size_t)n * DIM + d] + (v[i] - mean) * rstd * g[d] + bta[d];
        y[(size_t)n * DIM + d] = val;
        ybf[(size_t)n * DIM + d] = __float2bfloat16(val);
    }
}

// ================= transpose fp32 [E][R][C] -> bf16 [E][C][R] =================
__global__ __launch_bounds__(256) void transpose_kernel(
    const float* __restrict__ in, __hip_bfloat16* __restrict__ out, int R, int C)
{
    const float* ie = in + (size_t)blockIdx.z * R * C;
    __hip_bfloat16* oe = out + (size_t)blockIdx.z * R * C;
    int c0 = blockIdx.x * 32, r0 = blockIdx.y * 32;
    __shared__ float tile[32][33];
    int t = threadIdx.x, i = t >> 3, j4 = (t & 7) * 4;
    float4 v4 = *(const float4*)(ie + (size_t)(r0 + i) * C + c0 + j4);
    tile[i][j4] = v4.x; tile[i][j4+1] = v4.y; tile[i][j4+2] = v4.z; tile[i][j4+3] = v4.w;
    __syncthreads();
    union { ushort u[4]; ushort4 v; } pk;
    #pragma unroll
    for (int l = 0; l < 4; ++l) {
        __hip_bfloat16 hb = __float2bfloat16(tile[j4 + l][i]);
        pk.u[l] = *(const ushort*)&hb;
    }
    *(ushort4*)((ushort*)oe + (size_t)(c0 + i) * R + r0 + j4) = pk.v;
}

// ================= gate: logits, top2, softmax weights, counts =================
__global__ __launch_bounds__(256) void gate_kernel(
    const float* __restrict__ y, const float* __restrict__ gW,
    int* __restrict__ topk_e, float* __restrict__ topk_w, int* __restrict__ cnt)
{
    int n = blockIdx.x, t = threadIdx.x;
    const float* yr = y + (size_t)n * DIM;
    float p[8] = {0.f,0.f,0.f,0.f,0.f,0.f,0.f,0.f};
    for (int d = t; d < DIM; d += 256) {
        float yv = yr[d];
        const float* w = gW + (size_t)d * NEXP;
        #pragma unroll
        for (int e = 0; e < 8; ++e) p[e] += yv * w[e];
    }
    #pragma unroll
    for (int e = 0; e < 8; ++e)
        #pragma unroll
        for (int off = 32; off; off >>= 1) p[e] += __shfl_down(p[e], off);
    __shared__ float lg[4][8];
    if ((t & 63) == 0) { int w = t >> 6;
        #pragma unroll
        for (int e = 0; e < 8; ++e) lg[w][e] = p[e]; }
    __syncthreads();
    if (t == 0) {
        float l[8];
        #pragma unroll
        for (int e = 0; e < 8; ++e) l[e] = lg[0][e] + lg[1][e] + lg[2][e] + lg[3][e];
        int e0 = 0; float v0 = l[0];
        for (int e = 1; e < 8; ++e) if (l[e] > v0) { v0 = l[e]; e0 = e; }
        int e1 = 0; float v1 = -1e30f;
        for (int e = 0; e < 8; ++e) if (e != e0 && l[e] > v1) { v1 = l[e]; e1 = e; }
        float z = expf(v1 - v0);
        float w0 = 1.f / (1.f + z), w1 = z / (1.f + z);
        topk_e[n * 2] = e0; topk_e[n * 2 + 1] = e1;
        topk_w[n * 2] = w0; topk_w[n * 2 + 1] = w1;
        atomicAdd(&cnt[e0], 1); atomicAdd(&cnt[e1], 1);
    }
}

__global__ void scan_kernel(const int* __restrict__ cnt, int* __restrict__ po, int* __restrict__ cursor)
{
    if (threadIdx.x == 0 && blockIdx.x == 0) {
        int acc = 0;
        for (int e = 0; e < 8; ++e) { po[e] = acc; cursor[e] = acc; acc += ((cnt[e] + 127) >> 7) << 7; }
        po[8] = acc;
    }
}

// scatter: also records slot_of[i] so the combine can gather instead of atomic-add
__global__ void scatter_kernel(const int* __restrict__ topk_e, const float* __restrict__ topk_w,
                               int* __restrict__ cursor, int* __restrict__ slot_token,
                               int* __restrict__ slot_of)
{
    int i = blockIdx.x * 256 + threadIdx.x;   // < 4096
    int e = topk_e[i];
    int pos = atomicAdd(&cursor[e], 1);
    slot_token[pos] = i >> 1;
    slot_of[i] = pos;
}

// ====== MoE GEMM1: h = relu(y W1[e] + b1[e]); LDS-free direct-load MFMA ======
// XCD-swizzled 1D grid (1280): xcd = flat&7; j = flat>>3; n_panel = (j&3)*8+xcd; m_panel = j>>2.
// Fragments loaded straight from global (64B/row granules); no barriers, no LDS conflicts;
// compiler software-pipelines loads across K with fine-grained vmcnt.
__global__ __launch_bounds__(256) void moe_gemm1(
    const __hip_bfloat16* __restrict__ ybf, const __hip_bfloat16* __restrict__ W1t,
    const float* __restrict__ b1, const int* __restrict__ po, const int* __restrict__ cnt,
    const int* __restrict__ slot_token, __hip_bfloat16* __restrict__ h)
{
    int flat = blockIdx.x;
    int xcd = flat & 7, j = flat >> 3;
    int n0 = (((j & 3) << 3) + xcd) * 128;
    int m0 = (j >> 2) * 128;
    int total = po[8];
    if (m0 >= total) return;
    int e = 0;
    for (int i = 0; i < 8; ++i) if (m0 >= po[i] && m0 < po[i + 1]) e = i;
    int valid = po[e] + cnt[e] - m0; if (valid > 128) valid = 128;
    int t = threadIdx.x, wave = t >> 6, lane = t & 63;
    int wr = (wave >> 1) * 64, wc = (wave & 1) * 64;
    int lrow = lane & 15, quad = lane >> 4;
    const __hip_bfloat16* pA[4];
    const __hip_bfloat16* pB[4];
    #pragma unroll
    for (int i = 0; i < 4; ++i) {
        int r = wr + i * 16 + lrow;
        int tk = slot_token[(r < valid) ? (m0 + r) : m0];
        pA[i] = ybf + (size_t)tk * DIM + quad * 8;
    }
    #pragma unroll
    for (int jj = 0; jj < 4; ++jj)
        pB[jj] = W1t + ((size_t)e * FF + n0 + wc + jj * 16 + lrow) * DIM + quad * 8;
    floatx4 acc[4][4];
    #pragma unroll
    for (int i = 0; i < 4; ++i)
        #pragma unroll
        for (int jj = 0; jj < 4; ++jj) acc[i][jj] = (floatx4){0.f, 0.f, 0.f, 0.f};
    #pragma unroll 2
    for (int k0 = 0; k0 < DIM; k0 += 32) {
        short8 a[4], b[4];
        #pragma unroll
        for (int i = 0; i < 4; ++i) a[i] = *(const short8*)(pA[i] + k0);
        #pragma unroll
        for (int jj = 0; jj < 4; ++jj) b[jj] = *(const short8*)(pB[jj] + k0);
        #pragma unroll
        for (int i = 0; i < 4; ++i)
            #pragma unroll
            for (int jj = 0; jj < 4; ++jj)
                acc[i][jj] = __builtin_amdgcn_mfma_f32_16x16x32_bf16(a[i], b[jj], acc[i][jj], 0, 0, 0);
    }
    #pragma unroll
    for (int i = 0; i < 4; ++i)
        #pragma unroll
        for (int jj = 0; jj < 4; ++jj) {
            int col = n0 + wc + jj * 16 + lrow;
            float bias = b1[e * FF + col];
            #pragma unroll
            for (int r = 0; r < 4; ++r) {
                int row = wr + i * 16 + quad * 4 + r;
                float vv = fmaxf(acc[i][jj][r] + bias, 0.f);
                h[(size_t)(m0 + row) * FF + col] = __float2bfloat16(vv);
            }
        }
}

// ====== MoE GEMM2: eo[slot] = h W2[e] (+b2 in kz=0); LDS-free direct-load MFMA ======
// XCD-swizzled 1D grid (640): xcd = flat&7 = n_panel; j = flat>>3; kz = j&1; m_panel = j>>1.
__global__ __launch_bounds__(256) void moe_gemm2(
    const __hip_bfloat16* __restrict__ h, const __hip_bfloat16* __restrict__ W2t,
    const float* __restrict__ b2, const int* __restrict__ po,
    float* __restrict__ eoA, float* __restrict__ eoB)
{
    int flat = blockIdx.x;
    int xcd = flat & 7, j = flat >> 3;
    int n0 = xcd * 128;
    int kz = j & 1;
    int m0 = (j >> 1) * 128;
    int total = po[8];
    if (m0 >= total) return;
    int e = 0;
    for (int i = 0; i < 8; ++i) if (m0 >= po[i] && m0 < po[i + 1]) e = i;
    int t = threadIdx.x, wave = t >> 6, lane = t & 63;
    int wr = (wave >> 1) * 64, wc = (wave & 1) * 64;
    int lrow = lane & 15, quad = lane >> 4;
    const __hip_bfloat16* pA[4];
    const __hip_bfloat16* pB[4];
    #pragma unroll
    for (int i = 0; i < 4; ++i)
        pA[i] = h + (size_t)(m0 + wr + i * 16 + lrow) * FF + quad * 8;
    #pragma unroll
    for (int jj = 0; jj < 4; ++jj)
        pB[jj] = W2t + ((size_t)e * DIM + n0 + wc + jj * 16 + lrow) * FF + quad * 8;
    floatx4 acc[4][4];
    #pragma unroll
    for (int i = 0; i < 4; ++i)
        #pragma unroll
        for (int jj = 0; jj < 4; ++jj) acc[i][jj] = (floatx4){0.f, 0.f, 0.f, 0.f};
    int kbeg = kz * (FF / 2), kend = kbeg + (FF / 2);
    #pragma unroll 2
    for (int k0 = kbeg; k0 < kend; k0 += 32) {
        short8 a[4], b[4];
        #pragma unroll
        for (int i = 0; i < 4; ++i) a[i] = *(const short8*)(pA[i] + k0);
        #pragma unroll
        for (int jj = 0; jj < 4; ++jj) b[jj] = *(const short8*)(pB[jj] + k0);
        #pragma unroll
        for (int i = 0; i < 4; ++i)
            #pragma unroll
            for (int jj = 0; jj < 4; ++jj)
                acc[i][jj] = __builtin_amdgcn_mfma_f32_16x16x32_bf16(a[i], b[jj], acc[i][jj], 0, 0, 0);
    }
    float* eo = kz ? eoB : eoA;
    #pragma unroll
    for (int i = 0; i < 4; ++i)
        #pragma unroll
        for (int jj = 0; jj < 4; ++jj) {
            int col = n0 + wc + jj * 16 + lrow;
            float bias = (kz == 0) ? b2[e * DIM + col] : 0.f;
            #pragma unroll
            for (int r = 0; r < 4; ++r) {
                int row = wr + i * 16 + quad * 4 + r;
                eo[(size_t)(m0 + row) * DIM + col] = acc[i][jj][r] + bias;
            }
        }
}

// ====== ln2 (+fused combine): out = y + LN(Σk w_k (eoA[s_k]+eoB[s_k]))*g+b ======
__global__ __launch_bounds__(256) void ln2_kernel(
    const float* __restrict__ y,
    const float* __restrict__ eoA, const float* __restrict__ eoB,
    const int* __restrict__ slot_of, const float* __restrict__ topk_w,
    const float* __restrict__ g, const float* __restrict__ bta, float* __restrict__ out)
{
    int n = blockIdx.x, t = threadIdx.x;
    int s0 = slot_of[n * 2], s1 = slot_of[n * 2 + 1];
    float w0 = topk_w[n * 2], w1 = topk_w[n * 2 + 1];
    const float* a0 = eoA + (size_t)s0 * DIM;
    const float* b0 = eoB + (size_t)s0 * DIM;
    const float* a1 = eoA + (size_t)s1 * DIM;
    const float* b1r = eoB + (size_t)s1 * DIM;
    float v[4]; float s = 0.f;
    #pragma unroll
    for (int i = 0; i < 4; ++i) {
        int c = t + i * 256;
        v[i] = w0 * (a0[c] + b0[c]) + w1 * (a1[c] + b1r[c]);
        s += v[i];
    }
    __shared__ float redA[4];
    #pragma unroll
    for (int off = 32; off; off >>= 1) s += __shfl_down(s, off);
    if ((t & 63) == 0) redA[t >> 6] = s;
    __syncthreads();
    float mean = (redA[0] + redA[1] + redA[2] + redA[3]) * (1.f / 1024.f);
    float s2 = 0.f;
    #pragma unroll
    for (int i = 0; i < 4; ++i) { float d = v[i] - mean; s2 += d * d; }
    __shared__ float redB[4];
    #pragma unroll
    for (int off = 32; off; off >>= 1) s2 += __shfl_down(s2, off);
    if ((t & 63) == 0) redB[t >> 6] = s2;
    __syncthreads();
    float rstd = rsqrtf((redB[0] + redB[1] + redB[2] + redB[3]) * (1.f / 1024.f) + 1e-5f);
    #pragma unroll
    for (int i = 0; i < 4; ++i) {
        int d = t + i * 256;
        out[(size_t)n * DIM + d] = y[(size_t)n * DIM + d] + (v[i] - mean) * rstd * g[d] + bta[d];
    }
}

extern "C" void kernel_launch(void* const* d_in, const int* in_sizes, int n_in,
                              void* d_out, int out_size, void* d_ws, size_t ws_size,
                              hipStream_t stream)
{
    const float* x    = (const float*)d_in[0];
    const float* Wq   = (const float*)d_in[1];
    const float* Wk   = (const float*)d_in[2];
    const float* Wv   = (const float*)d_in[3];
    const float* gW   = (const float*)d_in[4];
    const float* W1   = (const float*)d_in[5];
    const float* b1   = (const float*)d_in[6];
    const float* W2   = (const float*)d_in[7];
    const float* b2   = (const float*)d_in[8];
    const float* ln1g = (const float*)d_in[9];
    const float* ln1b = (const float*)d_in[10];
    const float* ln2g = (const float*)d_in[11];
    const float* ln2b = (const float*)d_in[12];
    float* out = (float*)d_out;

    char* ws = (char*)d_ws;
    float* Q    = (float*)(ws + OFF_Q);
    float* Kb   = (float*)(ws + OFF_K);
    float* V    = (float*)(ws + OFF_V);
    float* attn = (float*)(ws + OFF_ATTN);
    float* attnB= (float*)(ws + OFF_ATTNB);   // aliases Q (dead after scores)
    float* y    = (float*)(ws + OFF_Y);
    __hip_bfloat16* ybf = (__hip_bfloat16*)(ws + OFF_YBF);
    __hip_bfloat16* W1t = (__hip_bfloat16*)(ws + OFF_W1T);
    int*   topk_e = (int*)(ws + OFF_TOPKE);
    float* topk_w = (float*)(ws + OFF_TOPKW);
    int*   cnt    = (int*)(ws + OFF_CNT);
    int*   po     = (int*)(ws + OFF_PO);
    int*   cur    = (int*)(ws + OFF_CUR);
    int*   slot_t = (int*)(ws + OFF_SLOTT);
    int*   slot_of= (int*)(ws + OFF_SLOTOF);
    float* S      = (float*)(ws + OFF_S);
    __hip_bfloat16* xhi  = (__hip_bfloat16*)(ws + OFF_XHI);
    __hip_bfloat16* xlo  = (__hip_bfloat16*)(ws + OFF_XLO);
    __hip_bfloat16* Wthi = (__hip_bfloat16*)(ws + OFF_WTHI);
    __hip_bfloat16* Wtlo = (__hip_bfloat16*)(ws + OFF_WTLO);
    __hip_bfloat16* W2t = (__hip_bfloat16*)(ws + OFF_W2T);
    __hip_bfloat16* h   = (__hip_bfloat16*)(ws + OFF_H);
    float* eoA = (float*)(ws + OFF_EOA);      // aliases W1t (dead after gemm1)
    float* eoB = (float*)(ws + OFF_EOB);

    hipMemsetAsync(cnt, 0, 32, stream);

    // QKV via bf16x2-split MFMA (inputs staged in the pre-scores S region)
    xsplit_kernel<<<2048, 256, 0, stream>>>(x, xhi, xlo);
    wsplit_kernel<<<dim3(2, 32, 48), 256, 0, stream>>>(Wq, Wk, Wv, Wthi, Wtlo);
    qkv_mfma<<<dim3(16, 16, 3), 256, 0, stream>>>(xhi, xlo, Wthi, Wtlo, Q, Kb, V);
    // attention (fp32 path; scores overwrite xhi/Wt* — dead after qkv_mfma)
    scores_kernel<<<dim3(36, 32), 256, 0, stream>>>(Q, Kb, S);
    softmax_kernel<<<NB * NHEAD * TSEQ, 256, 0, stream>>>(S);
    pv_kernel<<<dim3(8, 32, 2), 256, 0, stream>>>(S, V, attn, attnB);
    ln1_kernel<<<NTOK, 256, 0, stream>>>(x, attn, attnB, ln1g, ln1b, y, ybf);
    gate_kernel<<<NTOK, 256, 0, stream>>>(y, gW, topk_e, topk_w, cnt);
    scan_kernel<<<1, 64, 0, stream>>>(cnt, po, cur);
    scatter_kernel<<<16, 256, 0, stream>>>(topk_e, topk_w, cur, slot_t, slot_of);
    // W1 transpose immediately before gemm1 -> W1t is L3-hot for it
    transpose_kernel<<<dim3(128, 32, 8), 256, 0, stream>>>(W1, W1t, DIM, FF);
    moe_gemm1<<<1280, 256, 0, stream>>>(ybf, W1t, b1, po, cnt, slot_t, h);
    // W2 transpose immediately before gemm2 -> W2t is L3-hot for it
    transpose_kernel<<<dim3(32, 128, 8), 256, 0, stream>>>(W2, W2t, FF, DIM);
    moe_gemm2<<<640, 256, 0, stream>>>(h, W2t, b2, po, eoA, eoB);
    ln2_kernel<<<NTOK, 256, 0, stream>>>(y, eoA, eoB, slot_of, topk_w, ln2g, ln2b, out);
}

// Round 6
// 754.292 us; speedup vs baseline: 1.2296x; 1.2296x over previous
//
#include <hip/hip_runtime.h>
#include <hip/hip_bf16.h>
#include <math.h>

typedef short short8 __attribute__((ext_vector_type(8)));
typedef float floatx4 __attribute__((ext_vector_type(4)));
typedef unsigned int u32_g __attribute__((address_space(1)));
typedef unsigned int u32_l __attribute__((address_space(3)));

__device__ __forceinline__ void gl_lds16(const void* g, void* l) {
    __builtin_amdgcn_global_load_lds((const u32_g*)g, (u32_l*)l, 16, 0, 0);
}

#define NB 2
#define TSEQ 1024
#define DIM 1024
#define NHEAD 16
#define HS 64
#define NEXP 8
#define FF 4096
#define NTOK (NB*TSEQ)          // 2048
#define MAXSLOT 5120            // 4096 + 8*127 padded, rounded to 40*128

// ---------------- workspace offsets (bytes) ----------------
#define OFF_Q      ((size_t)0)           // 8MB; dead after scores -> reused as attnB (pv z=1 partial)
#define OFF_K      ((size_t)8388608)
#define OFF_V      ((size_t)16777216)
#define OFF_ATTN   ((size_t)25165824)
#define OFF_Y      ((size_t)33554432)
#define OFF_YBF    ((size_t)41943040)
#define OFF_W1T    ((size_t)46137344)    // 64MB bf16 [E][FF][D]; dead after gemm1 -> eoA/eoB
#define OFF_MOE    ((size_t)113246208)   // now only slot_of (16KB)
#define OFF_TOPKE  ((size_t)121634816)
#define OFF_TOPKW  ((size_t)121651200)
#define OFF_CNT    ((size_t)121667584)
#define OFF_PO     ((size_t)121667648)
#define OFF_CUR    ((size_t)121667712)
#define OFF_SLOTT  ((size_t)121667776)
#define OFF_SLOTW  ((size_t)121688256)
#define OFF_S      ((size_t)121708800)   // 128MB fp32 scores/probs
// Dead-time reuse of the S region:
#define OFF_XHI    (OFF_S)
#define OFF_XLO    (OFF_S + 4194304)
#define OFF_WTHI   (OFF_S + 8388608)     // 6MB bf16 [3][1024][1024]
#define OFF_WTLO   (OFF_S + 14680064)
#define OFF_W2T    (OFF_S)               // 64MB bf16 [E][D][FF]
#define OFF_H      (OFF_S + 67108864)    // 40MB bf16 [MAXSLOT][FF]

#define OFF_ATTNB  (OFF_Q)               // pv z=1 partial output
#define OFF_SLOTOF (OFF_MOE)             // [4096] int: slot index per (token,k)
#define OFF_EOA    (OFF_W1T)             // 21MB fp32 [MAXSLOT][D] (split-K kz=0, includes b2)
#define OFF_EOB    (OFF_W1T + 20971520)  // 21MB fp32 (kz=1)

// ================= split x into bf16 hi/lo =================
__global__ __launch_bounds__(256) void xsplit_kernel(
    const float* __restrict__ x, __hip_bfloat16* __restrict__ xhi, __hip_bfloat16* __restrict__ xlo)
{
    int idx = (blockIdx.x * 256 + threadIdx.x) * 4;
    float4 v = *(const float4*)(x + idx);
    float vv[4] = {v.x, v.y, v.z, v.w};
    union { ushort u[4]; ushort4 q; } hi, lo;
    #pragma unroll
    for (int l = 0; l < 4; ++l) {
        __hip_bfloat16 hb = __float2bfloat16(vv[l]);
        hi.u[l] = *(const ushort*)&hb;
        float r = vv[l] - __bfloat162float(hb);
        __hip_bfloat16 lb = __float2bfloat16(r);
        lo.u[l] = *(const ushort*)&lb;
    }
    *(ushort4*)((ushort*)xhi + idx) = hi.q;
    *(ushort4*)((ushort*)xlo + idx) = lo.q;
}

// ====== transpose Wq/Wk/Wv [16][1024][64] -> Wt[mat][(h*64+f)][d] bf16 hi/lo ======
__global__ __launch_bounds__(256) void wsplit_kernel(
    const float* __restrict__ Wq, const float* __restrict__ Wk, const float* __restrict__ Wv,
    __hip_bfloat16* __restrict__ Wthi, __hip_bfloat16* __restrict__ Wtlo)
{
    int z = blockIdx.z, mat = z >> 4, hh = z & 15;
    const float* W = (mat == 0) ? Wq : ((mat == 1) ? Wk : Wv);
    const float* slab = W + (size_t)hh * DIM * HS;              // [1024][64]
    ushort* ohi = (ushort*)Wthi + (size_t)mat * (DIM * DIM) + (size_t)hh * HS * DIM;
    ushort* olo = (ushort*)Wtlo + (size_t)mat * (DIM * DIM) + (size_t)hh * HS * DIM;
    int c0 = blockIdx.x * 32, r0 = blockIdx.y * 32;
    __shared__ float tile[32][33];
    int t = threadIdx.x, i = t >> 3, j4 = (t & 7) * 4;
    float4 v4 = *(const float4*)(slab + (size_t)(r0 + i) * HS + c0 + j4);
    tile[i][j4] = v4.x; tile[i][j4+1] = v4.y; tile[i][j4+2] = v4.z; tile[i][j4+3] = v4.w;
    __syncthreads();
    union { ushort u[4]; ushort4 q; } hi, lo;
    #pragma unroll
    for (int l = 0; l < 4; ++l) {
        float xv = tile[j4 + l][i];
        __hip_bfloat16 hb = __float2bfloat16(xv);
        hi.u[l] = *(const ushort*)&hb;
        float r = xv - __bfloat162float(hb);
        __hip_bfloat16 lb = __float2bfloat16(r);
        lo.u[l] = *(const ushort*)&lb;
    }
    *(ushort4*)(ohi + (size_t)(c0 + i) * DIM + r0 + j4) = hi.q;
    *(ushort4*)(olo + (size_t)(c0 + i) * DIM + r0 + j4) = lo.q;
}

// ================= QKV via bf16x2-split MFMA (XOR-swizzled LDS) =================
// LDS slot (row, s) holds global chunk s ^ ((row>>1)&3); readers apply the same XOR.
__global__ __launch_bounds__(256) void qkv_mfma(
    const __hip_bfloat16* __restrict__ xhi, const __hip_bfloat16* __restrict__ xlo,
    const __hip_bfloat16* __restrict__ Wthi, const __hip_bfloat16* __restrict__ Wtlo,
    float* __restrict__ Q, float* __restrict__ Kb, float* __restrict__ V)
{
    int mat = blockIdx.z;
    const __hip_bfloat16* Bhg = Wthi + (size_t)mat * (DIM * DIM);
    const __hip_bfloat16* Blg = Wtlo + (size_t)mat * (DIM * DIM);
    float* O = (mat == 0) ? Q : ((mat == 1) ? Kb : V);
    int n0 = blockIdx.x * 64, m0 = blockIdx.y * 128;
    int t = threadIdx.x, wave = t >> 6, lane = t & 63;
    __shared__ __hip_bfloat16 Ah[128][32];
    __shared__ __hip_bfloat16 Al[128][32];
    __shared__ __hip_bfloat16 Bh[64][32];
    __shared__ __hip_bfloat16 Bl[64][32];
    const __hip_bfloat16 *gAh[2], *gAl[2];
    __hip_bfloat16 *lAh[2], *lAl[2];
    #pragma unroll
    for (int p = 0; p < 2; ++p) {
        int lin = p * 256 + t, row = lin >> 2, s = lin & 3;
        int sg = s ^ ((row >> 1) & 3);                      // XOR swizzle
        gAh[p] = xhi + (size_t)(m0 + row) * DIM + sg * 8;
        gAl[p] = xlo + (size_t)(m0 + row) * DIM + sg * 8;
        int cb = p * 256 + wave * 64;
        lAh[p] = &Ah[0][0] + (size_t)cb * 8;
        lAl[p] = &Al[0][0] + (size_t)cb * 8;
    }
    int brow = t >> 2, bs = t & 3;
    int bsg = bs ^ ((brow >> 1) & 3);
    const __hip_bfloat16* gBh = Bhg + (size_t)(n0 + brow) * DIM + bsg * 8;
    const __hip_bfloat16* gBl = Blg + (size_t)(n0 + brow) * DIM + bsg * 8;
    __hip_bfloat16* lBh = &Bh[0][0] + (size_t)(wave * 64) * 8;
    __hip_bfloat16* lBl = &Bl[0][0] + (size_t)(wave * 64) * 8;

    int wr = (wave >> 1) * 64, wcl = (wave & 1) * 32;
    int lrow = lane & 15, quad = lane >> 4;
    int sq = (quad ^ ((lrow >> 1) & 3)) * 8;                // reader swizzle (rows ≡ lrow mod 16)
    floatx4 acc[4][2];
    #pragma unroll
    for (int i = 0; i < 4; ++i)
        #pragma unroll
        for (int j = 0; j < 2; ++j) acc[i][j] = (floatx4){0.f, 0.f, 0.f, 0.f};

    for (int k0 = 0; k0 < DIM; k0 += 32) {
        __syncthreads();
        gl_lds16(gAh[0] + k0, lAh[0]); gl_lds16(gAh[1] + k0, lAh[1]);
        gl_lds16(gAl[0] + k0, lAl[0]); gl_lds16(gAl[1] + k0, lAl[1]);
        gl_lds16(gBh + k0, lBh);       gl_lds16(gBl + k0, lBl);
        __syncthreads();
        short8 ah[4], al[4], bh[2], bl[2];
        #pragma unroll
        for (int i = 0; i < 4; ++i) {
            ah[i] = *(const short8*)(&Ah[wr + i * 16 + lrow][sq]);
            al[i] = *(const short8*)(&Al[wr + i * 16 + lrow][sq]);
        }
        #pragma unroll
        for (int j = 0; j < 2; ++j) {
            bh[j] = *(const short8*)(&Bh[wcl + j * 16 + lrow][sq]);
            bl[j] = *(const short8*)(&Bl[wcl + j * 16 + lrow][sq]);
        }
        #pragma unroll
        for (int i = 0; i < 4; ++i)
            #pragma unroll
            for (int j = 0; j < 2; ++j) {
                acc[i][j] = __builtin_amdgcn_mfma_f32_16x16x32_bf16(ah[i], bh[j], acc[i][j], 0, 0, 0);
                acc[i][j] = __builtin_amdgcn_mfma_f32_16x16x32_bf16(ah[i], bl[j], acc[i][j], 0, 0, 0);
                acc[i][j] = __builtin_amdgcn_mfma_f32_16x16x32_bf16(al[i], bh[j], acc[i][j], 0, 0, 0);
            }
    }
    #pragma unroll
    for (int i = 0; i < 4; ++i)
        #pragma unroll
        for (int j = 0; j < 2; ++j) {
            int ng = n0 + wcl + j * 16 + lrow;
            int hh = ng >> 6, f = ng & 63;
            #pragma unroll
            for (int r = 0; r < 4; ++r) {
                int mg = m0 + wr + i * 16 + quad * 4 + r;
                int bb = mg >> 10, tt = mg & 1023;
                O[(((size_t)bb * NHEAD + hh) * TSEQ + tt) * HS + f] = acc[i][j][r];
            }
        }
}

// ================= causal scores: S = Q K^T / 32 (lower tiles) =================
__global__ __launch_bounds__(256) void scores_kernel(
    const float* __restrict__ Q, const float* __restrict__ Kb, float* __restrict__ S)
{
    int tri = blockIdx.x, bh = blockIdx.y;
    int mt = 0; while (((mt + 1) * (mt + 2)) / 2 <= tri) ++mt;
    int nt = tri - (mt * (mt + 1)) / 2;
    int m0 = mt * 128, n0 = nt * 128;
    const float* Qb = Q + (size_t)bh * TSEQ * HS;
    const float* Kh = Kb + (size_t)bh * TSEQ * HS;
    float* Sb = S + (size_t)bh * TSEQ * TSEQ;
    __shared__ float As[16][132];
    __shared__ float Bs[16][132];
    int t = threadIdx.x, tx = t & 15, ty = t >> 4;
    float acc[8][8] = {{0.f}};
    for (int k0 = 0; k0 < HS; k0 += 16) {
        #pragma unroll
        for (int pss = 0; pss < 2; ++pss) {
            int lin = pss * 256 + t, m = lin >> 2, c = lin & 3;
            float4 v4 = *(const float4*)(Qb + (size_t)(m0 + m) * HS + k0 + c * 4);
            As[c*4+0][m] = v4.x; As[c*4+1][m] = v4.y; As[c*4+2][m] = v4.z; As[c*4+3][m] = v4.w;
        }
        #pragma unroll
        for (int pss = 0; pss < 2; ++pss) {
            int lin = pss * 256 + t, s = lin >> 2, c = lin & 3;
            float4 v4 = *(const float4*)(Kh + (size_t)(n0 + s) * HS + k0 + c * 4);
            Bs[c*4+0][s] = v4.x; Bs[c*4+1][s] = v4.y; Bs[c*4+2][s] = v4.z; Bs[c*4+3][s] = v4.w;
        }
        __syncthreads();
        #pragma unroll
        for (int kk = 0; kk < 16; ++kk) {
            float a[8], b[8];
            *(float4*)a       = *(const float4*)(&As[kk][ty * 4]);
            *(float4*)(a + 4) = *(const float4*)(&As[kk][64 + ty * 4]);
            *(float4*)b       = *(const float4*)(&Bs[kk][tx * 4]);
            *(float4*)(b + 4) = *(const float4*)(&Bs[kk][64 + tx * 4]);
            #pragma unroll
            for (int i = 0; i < 8; ++i)
                #pragma unroll
                for (int j = 0; j < 8; ++j) acc[i][j] += a[i] * b[j];
        }
        __syncthreads();
    }
    const float scale = 0.03125f;  // D^-0.5
    #pragma unroll
    for (int i = 0; i < 8; ++i) {
        int r = m0 + ((i < 4) ? ty * 4 + i : 64 + ty * 4 + (i - 4));
        #pragma unroll
        for (int jg = 0; jg < 2; ++jg) {
            int cb = n0 + ((jg == 0) ? tx * 4 : 64 + tx * 4);
            float4 v4 = make_float4(acc[i][jg*4+0]*scale, acc[i][jg*4+1]*scale,
                                    acc[i][jg*4+2]*scale, acc[i][jg*4+3]*scale);
            *(float4*)(Sb + (size_t)r * TSEQ + cb) = v4;
        }
    }
}

// ====== causal row softmax, in place; writes only up to the causal tile edge ======
__global__ __launch_bounds__(256) void softmax_kernel(float* __restrict__ S)
{
    int row = blockIdx.x, bh = row >> 10, r = row & 1023;
    float* p = S + ((size_t)bh * TSEQ + r) * TSEQ;
    int len = r + 1, t = threadIdx.x;
    int klim = (r & ~127) + 128;   // pv reads cols [0, klim) for this row
    float v[4]; float mx = -1e30f;
    #pragma unroll
    for (int i = 0; i < 4; ++i) { int c = t + i * 256; v[i] = (c < len) ? p[c] : -1e30f; mx = fmaxf(mx, v[i]); }
    __shared__ float redA[4];
    #pragma unroll
    for (int off = 32; off; off >>= 1) mx = fmaxf(mx, __shfl_down(mx, off));
    if ((t & 63) == 0) redA[t >> 6] = mx;
    __syncthreads();
    mx = fmaxf(fmaxf(redA[0], redA[1]), fmaxf(redA[2], redA[3]));
    float sum = 0.f;
    #pragma unroll
    for (int i = 0; i < 4; ++i) { int c = t + i * 256; float e = (c < len) ? expf(v[i] - mx) : 0.f; v[i] = e; sum += e; }
    __shared__ float redB[4];
    #pragma unroll
    for (int off = 32; off; off >>= 1) sum += __shfl_down(sum, off);
    if ((t & 63) == 0) redB[t >> 6] = sum;
    __syncthreads();
    float inv = 1.f / (redB[0] + redB[1] + redB[2] + redB[3]);
    #pragma unroll
    for (int i = 0; i < 4; ++i) { int c = t + i * 256; if (c < klim) p[c] = v[i] * inv; }
}

// ====== PV: attn = P V, split-K z=2 (z=0 -> attn, z=1 -> attnB; ln1 sums) ======
__global__ __launch_bounds__(256) void pv_kernel(
    const float* __restrict__ S, const float* __restrict__ V,
    float* __restrict__ attn, float* __restrict__ attnB)
{
    int mt = blockIdx.x, bh = blockIdx.y, z = blockIdx.z;
    int m0 = mt * 128;
    int half = (m0 >> 1) + 64;                 // multiple of 64
    int kbeg = z ? half : 0;
    int kend = z ? (m0 + 128) : half;
    float* O = z ? attnB : attn;
    const float* P = S + (size_t)bh * TSEQ * TSEQ;
    const float* Vb = V + (size_t)bh * TSEQ * HS;
    __shared__ float As[16][132];
    __shared__ float Bs[16][68];
    int t = threadIdx.x, tx = t & 15, ty = t >> 4;
    float acc[8][4] = {{0.f}};
    for (int k0 = kbeg; k0 < kend; k0 += 16) {
        #pragma unroll
        for (int pss = 0; pss < 2; ++pss) {
            int lin = pss * 256 + t, m = lin >> 2, c = lin & 3;
            float4 v4 = *(const float4*)(P + (size_t)(m0 + m) * TSEQ + k0 + c * 4);
            As[c*4+0][m] = v4.x; As[c*4+1][m] = v4.y; As[c*4+2][m] = v4.z; As[c*4+3][m] = v4.w;
        }
        { int kk = t >> 4, c = t & 15;
          float4 v4 = *(const float4*)(Vb + (size_t)(k0 + kk) * HS + c * 4);
          *(float4*)(&Bs[kk][c * 4]) = v4; }
        __syncthreads();
        #pragma unroll
        for (int kk = 0; kk < 16; ++kk) {
            float a[8], b[4];
            *(float4*)a       = *(const float4*)(&As[kk][ty * 4]);
            *(float4*)(a + 4) = *(const float4*)(&As[kk][64 + ty * 4]);
            *(float4*)b       = *(const float4*)(&Bs[kk][tx * 4]);
            #pragma unroll
            for (int i = 0; i < 8; ++i)
                #pragma unroll
                for (int j = 0; j < 4; ++j) acc[i][j] += a[i] * b[j];
        }
        __syncthreads();
    }
    int b = bh >> 4, hh = bh & 15;
    #pragma unroll
    for (int i = 0; i < 8; ++i) {
        int r = m0 + ((i < 4) ? ty * 4 + i : 64 + ty * 4 + (i - 4));
        float4 v4 = make_float4(acc[i][0], acc[i][1], acc[i][2], acc[i][3]);
        *(float4*)(O + ((size_t)b * TSEQ + r) * DIM + hh * HS + tx * 4) = v4;
    }
}

// ====== ln1: y = x + layernorm(attn+attnB)*g+b; also y_bf16 ======
__global__ __launch_bounds__(256) void ln1_kernel(
    const float* __restrict__ x, const float* __restrict__ attn, const float* __restrict__ attnB,
    const float* __restrict__ g, const float* __restrict__ bta,
    float* __restrict__ y, __hip_bfloat16* __restrict__ ybf)
{
    int n = blockIdx.x, t = threadIdx.x;
    const float* a = attn + (size_t)n * DIM;
    const float* aB = attnB + (size_t)n * DIM;
    float v[4]; float s = 0.f;
    #pragma unroll
    for (int i = 0; i < 4; ++i) { int c = t + i * 256; v[i] = a[c] + aB[c]; s += v[i]; }
    __shared__ float redA[4];
    #pragma unroll
    for (int off = 32; off; off >>= 1) s += __shfl_down(s, off);
    if ((t & 63) == 0) redA[t >> 6] = s;
    __syncthreads();
    float mean = (redA[0] + redA[1] + redA[2] + redA[3]) * (1.f / 1024.f);
    float s2 = 0.f;
    #pragma unroll
    for (int i = 0; i < 4; ++i) { float d = v[i] - mean; s2 += d * d; }
    __shared__ float redB[4];
    #pragma unroll
    for (int off = 32; off; off >>= 1) s2 += __shfl_down(s2, off);
    if ((t & 63) == 0) redB[t >> 6] = s2;
    __syncthreads();
    float rstd = rsqrtf((redB[0] + redB[1] + redB[2] + redB[3]) * (1.f / 1024.f) + 1e-5f);
    #pragma unroll
    for (int i = 0; i < 4; ++i) {
        int d = t + i * 256;
        float val = x[(size_t)n * DIM + d] + (v[i] - mean) * rstd * g[d] + bta[d];
        y[(size_t)n * DIM + d] = val;
        ybf[(size_t)n * DIM + d] = __float2bfloat16(val);
    }
}

// ================= transpose fp32 [E][R][C] -> bf16 [E][C][R] =================
__global__ __launch_bounds__(256) void transpose_kernel(
    const float* __restrict__ in, __hip_bfloat16* __restrict__ out, int R, int C)
{
    const float* ie = in + (size_t)blockIdx.z * R * C;
    __hip_bfloat16* oe = out + (size_t)blockIdx.z * R * C;
    int c0 = blockIdx.x * 32, r0 = blockIdx.y * 32;
    __shared__ float tile[32][33];
    int t = threadIdx.x, i = t >> 3, j4 = (t & 7) * 4;
    float4 v4 = *(const float4*)(ie + (size_t)(r0 + i) * C + c0 + j4);
    tile[i][j4] = v4.x; tile[i][j4+1] = v4.y; tile[i][j4+2] = v4.z; tile[i][j4+3] = v4.w;
    __syncthreads();
    union { ushort u[4]; ushort4 v; } pk;
    #pragma unroll
    for (int l = 0; l < 4; ++l) {
        __hip_bfloat16 hb = __float2bfloat16(tile[j4 + l][i]);
        pk.u[l] = *(const ushort*)&hb;
    }
    *(ushort4*)((ushort*)oe + (size_t)(c0 + i) * R + r0 + j4) = pk.v;
}

// ================= gate: logits, top2, softmax weights, counts =================
__global__ __launch_bounds__(256) void gate_kernel(
    const float* __restrict__ y, const float* __restrict__ gW,
    int* __restrict__ topk_e, float* __restrict__ topk_w, int* __restrict__ cnt)
{
    int n = blockIdx.x, t = threadIdx.x;
    const float* yr = y + (size_t)n * DIM;
    float p[8] = {0.f,0.f,0.f,0.f,0.f,0.f,0.f,0.f};
    for (int d = t; d < DIM; d += 256) {
        float yv = yr[d];
        const float* w = gW + (size_t)d * NEXP;
        #pragma unroll
        for (int e = 0; e < 8; ++e) p[e] += yv * w[e];
    }
    #pragma unroll
    for (int e = 0; e < 8; ++e)
        #pragma unroll
        for (int off = 32; off; off >>= 1) p[e] += __shfl_down(p[e], off);
    __shared__ float lg[4][8];
    if ((t & 63) == 0) { int w = t >> 6;
        #pragma unroll
        for (int e = 0; e < 8; ++e) lg[w][e] = p[e]; }
    __syncthreads();
    if (t == 0) {
        float l[8];
        #pragma unroll
        for (int e = 0; e < 8; ++e) l[e] = lg[0][e] + lg[1][e] + lg[2][e] + lg[3][e];
        int e0 = 0; float v0 = l[0];
        for (int e = 1; e < 8; ++e) if (l[e] > v0) { v0 = l[e]; e0 = e; }
        int e1 = 0; float v1 = -1e30f;
        for (int e = 0; e < 8; ++e) if (e != e0 && l[e] > v1) { v1 = l[e]; e1 = e; }
        float z = expf(v1 - v0);
        float w0 = 1.f / (1.f + z), w1 = z / (1.f + z);
        topk_e[n * 2] = e0; topk_e[n * 2 + 1] = e1;
        topk_w[n * 2] = w0; topk_w[n * 2 + 1] = w1;
        atomicAdd(&cnt[e0], 1); atomicAdd(&cnt[e1], 1);
    }
}

__global__ void scan_kernel(const int* __restrict__ cnt, int* __restrict__ po, int* __restrict__ cursor)
{
    if (threadIdx.x == 0 && blockIdx.x == 0) {
        int acc = 0;
        for (int e = 0; e < 8; ++e) { po[e] = acc; cursor[e] = acc; acc += ((cnt[e] + 127) >> 7) << 7; }
        po[8] = acc;
    }
}

// scatter: also records slot_of[i] so the combine can gather instead of atomic-add
__global__ void scatter_kernel(const int* __restrict__ topk_e, const float* __restrict__ topk_w,
                               int* __restrict__ cursor, int* __restrict__ slot_token,
                               int* __restrict__ slot_of)
{
    int i = blockIdx.x * 256 + threadIdx.x;   // < 4096
    int e = topk_e[i];
    int pos = atomicAdd(&cursor[e], 1);
    slot_token[pos] = i >> 1;
    slot_of[i] = pos;
}

// ====== MoE GEMM1: h = relu(y W1[e] + b1[e]); LDS staging + XOR swizzle ======
// LDS slot (row, s) holds global chunk s ^ (row&7); readers XOR with lrow&7 -> 2-way banks.
__global__ __launch_bounds__(256) void moe_gemm1(
    const __hip_bfloat16* __restrict__ ybf, const __hip_bfloat16* __restrict__ W1t,
    const float* __restrict__ b1, const int* __restrict__ po, const int* __restrict__ cnt,
    const int* __restrict__ slot_token, __hip_bfloat16* __restrict__ h)
{
    int flat = blockIdx.x;
    int xcd = flat & 7, j = flat >> 3;
    int n0 = (((j & 3) << 3) + xcd) * 128;
    int m0 = (j >> 2) * 128;
    int total = po[8];
    if (m0 >= total) return;
    int e = 0;
    for (int i = 0; i < 8; ++i) if (m0 >= po[i] && m0 < po[i + 1]) e = i;
    int valid = po[e] + cnt[e] - m0; if (valid > 128) valid = 128;
    int t = threadIdx.x, wave = t >> 6, lane = t & 63;
    __shared__ int tok[128];
    __shared__ __hip_bfloat16 As[128][64];
    __shared__ __hip_bfloat16 Bs[128][64];
    if (t < 128) tok[t] = (t < valid) ? slot_token[m0 + t] : slot_token[m0];
    __syncthreads();
    const __hip_bfloat16 *gA[4], *gB[4];
    __hip_bfloat16 *lA[4], *lB[4];
    #pragma unroll
    for (int p = 0; p < 4; ++p) {
        int lin = p * 256 + t, row = lin >> 3, seg = lin & 7;
        int sg = seg ^ (row & 7);                                 // XOR swizzle
        gA[p] = ybf + (size_t)tok[row] * DIM + sg * 8;
        gB[p] = W1t + ((size_t)e * FF + n0 + row) * DIM + sg * 8;
        int cb = p * 256 + wave * 64;
        lA[p] = &As[0][0] + (size_t)cb * 8;
        lB[p] = &Bs[0][0] + (size_t)cb * 8;
    }
    int wr = (wave >> 1) * 64, wc = (wave & 1) * 64;
    int lrow = lane & 15, quad = lane >> 4;
    floatx4 acc[4][4];
    #pragma unroll
    for (int i = 0; i < 4; ++i)
        #pragma unroll
        for (int j2 = 0; j2 < 4; ++j2) acc[i][j2] = (floatx4){0.f, 0.f, 0.f, 0.f};
    for (int k0 = 0; k0 < DIM; k0 += 64) {
        __syncthreads();
        #pragma unroll
        for (int p = 0; p < 4; ++p) { gl_lds16(gA[p] + k0, lA[p]); gl_lds16(gB[p] + k0, lB[p]); }
        __syncthreads();
        #pragma unroll
        for (int ks = 0; ks < 2; ++ks) {
            int sA = (((ks * 4 + quad) ^ (lrow & 7))) * 8;        // reader swizzle
            short8 a[4], b[4];
            #pragma unroll
            for (int i = 0; i < 4; ++i) a[i] = *(const short8*)(&As[wr + i * 16 + lrow][sA]);
            #pragma unroll
            for (int j2 = 0; j2 < 4; ++j2) b[j2] = *(const short8*)(&Bs[wc + j2 * 16 + lrow][sA]);
            #pragma unroll
            for (int i = 0; i < 4; ++i)
                #pragma unroll
                for (int j2 = 0; j2 < 4; ++j2)
                    acc[i][j2] = __builtin_amdgcn_mfma_f32_16x16x32_bf16(a[i], b[j2], acc[i][j2], 0, 0, 0);
        }
    }
    #pragma unroll
    for (int i = 0; i < 4; ++i)
        #pragma unroll
        for (int j2 = 0; j2 < 4; ++j2) {
            int col = n0 + wc + j2 * 16 + lrow;
            float bias = b1[e * FF + col];
            #pragma unroll
            for (int r = 0; r < 4; ++r) {
                int row = wr + i * 16 + quad * 4 + r;
                float vv = fmaxf(acc[i][j2][r] + bias, 0.f);
                h[(size_t)(m0 + row) * FF + col] = __float2bfloat16(vv);
            }
        }
}

// ====== MoE GEMM2: eo[slot] = h W2[e] (+b2 in kz=0); LDS staging + XOR swizzle ======
__global__ __launch_bounds__(256) void moe_gemm2(
    const __hip_bfloat16* __restrict__ h, const __hip_bfloat16* __restrict__ W2t,
    const float* __restrict__ b2, const int* __restrict__ po,
    float* __restrict__ eoA, float* __restrict__ eoB)
{
    int flat = blockIdx.x;
    int xcd = flat & 7, j = flat >> 3;
    int n0 = xcd * 128;
    int kz = j & 1;
    int m0 = (j >> 1) * 128;
    int total = po[8];
    if (m0 >= total) return;
    int e = 0;
    for (int i = 0; i < 8; ++i) if (m0 >= po[i] && m0 < po[i + 1]) e = i;
    int t = threadIdx.x, wave = t >> 6, lane = t & 63;
    __shared__ __hip_bfloat16 As[128][64];
    __shared__ __hip_bfloat16 Bs[128][64];
    const __hip_bfloat16 *gA[4], *gB[4];
    __hip_bfloat16 *lA[4], *lB[4];
    #pragma unroll
    for (int p = 0; p < 4; ++p) {
        int lin = p * 256 + t, row = lin >> 3, seg = lin & 7;
        int sg = seg ^ (row & 7);                                 // XOR swizzle
        gA[p] = h + (size_t)(m0 + row) * FF + sg * 8;
        gB[p] = W2t + ((size_t)e * DIM + n0 + row) * FF + sg * 8;
        int cb = p * 256 + wave * 64;
        lA[p] = &As[0][0] + (size_t)cb * 8;
        lB[p] = &Bs[0][0] + (size_t)cb * 8;
    }
    int wr = (wave >> 1) * 64, wc = (wave & 1) * 64;
    int lrow = lane & 15, quad = lane >> 4;
    floatx4 acc[4][4];
    #pragma unroll
    for (int i = 0; i < 4; ++i)
        #pragma unroll
        for (int j2 = 0; j2 < 4; ++j2) acc[i][j2] = (floatx4){0.f, 0.f, 0.f, 0.f};
    int kbeg = kz * (FF / 2), kend = kbeg + (FF / 2);
    for (int k0 = kbeg; k0 < kend; k0 += 64) {
        __syncthreads();
        #pragma unroll
        for (int p = 0; p < 4; ++p) { gl_lds16(gA[p] + k0, lA[p]); gl_lds16(gB[p] + k0, lB[p]); }
        __syncthreads();
        #pragma unroll
        for (int ks = 0; ks < 2; ++ks) {
            int sA = (((ks * 4 + quad) ^ (lrow & 7))) * 8;        // reader swizzle
            short8 a[4], b[4];
            #pragma unroll
            for (int i = 0; i < 4; ++i) a[i] = *(const short8*)(&As[wr + i * 16 + lrow][sA]);
            #pragma unroll
            for (int j2 = 0; j2 < 4; ++j2) b[j2] = *(const short8*)(&Bs[wc + j2 * 16 + lrow][sA]);
            #pragma unroll
            for (int i = 0; i < 4; ++i)
                #pragma unroll
                for (int j2 = 0; j2 < 4; ++j2)
                    acc[i][j2] = __builtin_amdgcn_mfma_f32_16x16x32_bf16(a[i], b[j2], acc[i][j2], 0, 0, 0);
        }
    }
    float* eo = kz ? eoB : eoA;
    #pragma unroll
    for (int i = 0; i < 4; ++i)
        #pragma unroll
        for (int j2 = 0; j2 < 4; ++j2) {
            int col = n0 + wc + j2 * 16 + lrow;
            float bias = (kz == 0) ? b2[e * DIM + col] : 0.f;
            #pragma unroll
            for (int r = 0; r < 4; ++r) {
                int row = wr + i * 16 + quad * 4 + r;
                eo[(size_t)(m0 + row) * DIM + col] = acc[i][j2][r] + bias;
            }
        }
}

// ====== ln2 (+fused combine): out = y + LN(Σk w_k (eoA[s_k]+eoB[s_k]))*g+b ======
__global__ __launch_bounds__(256) void ln2_kernel(
    const float* __restrict__ y,
    const float* __restrict__ eoA, const float* __restrict__ eoB,
    const int* __restrict__ slot_of, const float* __restrict__ topk_w,
    const float* __restrict__ g, const float* __restrict__ bta, float* __restrict__ out)
{
    int n = blockIdx.x, t = threadIdx.x;
    int s0 = slot_of[n * 2], s1 = slot_of[n * 2 + 1];
    float w0 = topk_w[n * 2], w1 = topk_w[n * 2 + 1];
    const float* a0 = eoA + (size_t)s0 * DIM;
    const float* b0 = eoB + (size_t)s0 * DIM;
    const float* a1 = eoA + (size_t)s1 * DIM;
    const float* b1r = eoB + (size_t)s1 * DIM;
    float v[4]; float s = 0.f;
    #pragma unroll
    for (int i = 0; i < 4; ++i) {
        int c = t + i * 256;
        v[i] = w0 * (a0[c] + b0[c]) + w1 * (a1[c] + b1r[c]);
        s += v[i];
    }
    __shared__ float redA[4];
    #pragma unroll
    for (int off = 32; off; off >>= 1) s += __shfl_down(s, off);
    if ((t & 63) == 0) redA[t >> 6] = s;
    __syncthreads();
    float mean = (redA[0] + redA[1] + redA[2] + redA[3]) * (1.f / 1024.f);
    float s2 = 0.f;
    #pragma unroll
    for (int i = 0; i < 4; ++i) { float d = v[i] - mean; s2 += d * d; }
    __shared__ float redB[4];
    #pragma unroll
    for (int off = 32; off; off >>= 1) s2 += __shfl_down(s2, off);
    if ((t & 63) == 0) redB[t >> 6] = s2;
    __syncthreads();
    float rstd = rsqrtf((redB[0] + redB[1] + redB[2] + redB[3]) * (1.f / 1024.f) + 1e-5f);
    #pragma unroll
    for (int i = 0; i < 4; ++i) {
        int d = t + i * 256;
        out[(size_t)n * DIM + d] = y[(size_t)n * DIM + d] + (v[i] - mean) * rstd * g[d] + bta[d];
    }
}

extern "C" void kernel_launch(void* const* d_in, const int* in_sizes, int n_in,
                              void* d_out, int out_size, void* d_ws, size_t ws_size,
                              hipStream_t stream)
{
    const float* x    = (const float*)d_in[0];
    const float* Wq   = (const float*)d_in[1];
    const float* Wk   = (const float*)d_in[2];
    const float* Wv   = (const float*)d_in[3];
    const float* gW   = (const float*)d_in[4];
    const float* W1   = (const float*)d_in[5];
    const float* b1   = (const float*)d_in[6];
    const float* W2   = (const float*)d_in[7];
    const float* b2   = (const float*)d_in[8];
    const float* ln1g = (const float*)d_in[9];
    const float* ln1b = (const float*)d_in[10];
    const float* ln2g = (const float*)d_in[11];
    const float* ln2b = (const float*)d_in[12];
    float* out = (float*)d_out;

    char* ws = (char*)d_ws;
    float* Q    = (float*)(ws + OFF_Q);
    float* Kb   = (float*)(ws + OFF_K);
    float* V    = (float*)(ws + OFF_V);
    float* attn = (float*)(ws + OFF_ATTN);
    float* attnB= (float*)(ws + OFF_ATTNB);   // aliases Q (dead after scores)
    float* y    = (float*)(ws + OFF_Y);
    __hip_bfloat16* ybf = (__hip_bfloat16*)(ws + OFF_YBF);
    __hip_bfloat16* W1t = (__hip_bfloat16*)(ws + OFF_W1T);
    int*   topk_e = (int*)(ws + OFF_TOPKE);
    float* topk_w = (float*)(ws + OFF_TOPKW);
    int*   cnt    = (int*)(ws + OFF_CNT);
    int*   po     = (int*)(ws + OFF_PO);
    int*   cur    = (int*)(ws + OFF_CUR);
    int*   slot_t = (int*)(ws + OFF_SLOTT);
    int*   slot_of= (int*)(ws + OFF_SLOTOF);
    float* S      = (float*)(ws + OFF_S);
    __hip_bfloat16* xhi  = (__hip_bfloat16*)(ws + OFF_XHI);
    __hip_bfloat16* xlo  = (__hip_bfloat16*)(ws + OFF_XLO);
    __hip_bfloat16* Wthi = (__hip_bfloat16*)(ws + OFF_WTHI);
    __hip_bfloat16* Wtlo = (__hip_bfloat16*)(ws + OFF_WTLO);
    __hip_bfloat16* W2t = (__hip_bfloat16*)(ws + OFF_W2T);
    __hip_bfloat16* h   = (__hip_bfloat16*)(ws + OFF_H);
    float* eoA = (float*)(ws + OFF_EOA);      // aliases W1t (dead after gemm1)
    float* eoB = (float*)(ws + OFF_EOB);

    hipMemsetAsync(cnt, 0, 32, stream);

    // QKV via bf16x2-split MFMA (inputs staged in the pre-scores S region)
    xsplit_kernel<<<2048, 256, 0, stream>>>(x, xhi, xlo);
    wsplit_kernel<<<dim3(2, 32, 48), 256, 0, stream>>>(Wq, Wk, Wv, Wthi, Wtlo);
    qkv_mfma<<<dim3(16, 16, 3), 256, 0, stream>>>(xhi, xlo, Wthi, Wtlo, Q, Kb, V);
    // attention (fp32 path; scores overwrite xhi/Wt* — dead after qkv_mfma)
    scores_kernel<<<dim3(36, 32), 256, 0, stream>>>(Q, Kb, S);
    softmax_kernel<<<NB * NHEAD * TSEQ, 256, 0, stream>>>(S);
    pv_kernel<<<dim3(8, 32, 2), 256, 0, stream>>>(S, V, attn, attnB);
    ln1_kernel<<<NTOK, 256, 0, stream>>>(x, attn, attnB, ln1g, ln1b, y, ybf);
    gate_kernel<<<NTOK, 256, 0, stream>>>(y, gW, topk_e, topk_w, cnt);
    scan_kernel<<<1, 64, 0, stream>>>(cnt, po, cur);
    scatter_kernel<<<16, 256, 0, stream>>>(topk_e, topk_w, cur, slot_t, slot_of);
    // W1 transpose immediately before gemm1 -> W1t is L3-hot for it
    transpose_kernel<<<dim3(128, 32, 8), 256, 0, stream>>>(W1, W1t, DIM, FF);
    moe_gemm1<<<1280, 256, 0, stream>>>(ybf, W1t, b1, po, cnt, slot_t, h);
    // W2 transpose immediately before gemm2 -> W2t is L3-hot for it
    transpose_kernel<<<dim3(32, 128, 8), 256, 0, stream>>>(W2, W2t, FF, DIM);
    moe_gemm2<<<640, 256, 0, stream>>>(h, W2t, b2, po, eoA, eoB);
    ln2_kernel<<<NTOK, 256, 0, stream>>>(y, eoA, eoB, slot_of, topk_w, ln2g, ln2b, out);
}